// Round 1
// baseline (701.633 us; speedup 1.0000x reference)
//
#include <hip/hip_runtime.h>
#include <hip/hip_bf16.h>
#include <float.h>

#define F 128          // hidden = H*C
#define HEADS 4
#define CPH 32

// ---------------- CSR build ----------------

__global__ void count_deg_kernel(const int* __restrict__ dst, int* __restrict__ deg, int E) {
    int i = blockIdx.x * blockDim.x + threadIdx.x;
    if (i < E) atomicAdd(&deg[dst[i]], 1);
}

__global__ void exscan_kernel(const int* __restrict__ deg, int* __restrict__ row_ptr, int n) {
    __shared__ int tmp[1024];
    __shared__ int carry_s;
    if (threadIdx.x == 0) carry_s = 0;
    __syncthreads();
    for (int base = 0; base < n; base += 1024) {
        int i = base + threadIdx.x;
        int v = (i < n) ? deg[i] : 0;
        tmp[threadIdx.x] = v;
        __syncthreads();
        for (int offs = 1; offs < 1024; offs <<= 1) {
            int add = (threadIdx.x >= offs) ? tmp[threadIdx.x - offs] : 0;
            __syncthreads();
            tmp[threadIdx.x] += add;
            __syncthreads();
        }
        int incl = tmp[threadIdx.x];
        if (i < n) row_ptr[i] = carry_s + incl - v;   // exclusive scan
        __syncthreads();
        if (threadIdx.x == 1023) carry_s += tmp[1023];
        __syncthreads();
    }
    if (threadIdx.x == 0) row_ptr[n] = carry_s;
}

// store src node id directly in dst-sorted order (kills one indirection level)
__global__ void scatter_kernel(const int* __restrict__ src, const int* __restrict__ dst,
                               const int* __restrict__ row_ptr, int* __restrict__ cursor,
                               int* __restrict__ srcs, int E) {
    int i = blockIdx.x * blockDim.x + threadIdx.x;
    if (i < E) {
        int d = dst[i];
        int pos = atomicAdd(&cursor[d], 1);
        srcs[row_ptr[d] + pos] = src[i];
    }
}

// ---------------- fp32 GEMM: Y[N,128] = X[N,128] @ W[128,128] + b ----------------
// W staged in LDS (64KB). 256 thr/block, 32 rows/block, 4x4 register tile per thread.

__global__ __launch_bounds__(256) void gemm128_kernel(
    const float* __restrict__ X, const float* __restrict__ W,
    const float* __restrict__ bias, float* __restrict__ Y, int N)
{
    __shared__ float Ws[F * F];
    for (int i = threadIdx.x; i < F * F; i += 256) Ws[i] = W[i];
    __syncthreads();
    int lane = threadIdx.x & 31;   // output col lane: cols lane + 32*j (conflict-free LDS)
    int grp  = threadIdx.x >> 5;   // row group 0..7, 4 rows each
    int row0 = blockIdx.x * 32 + grp * 4;
    if (row0 + 4 <= N) {
        float acc[4][4] = {};
        for (int k = 0; k < F; k += 4) {
            float4 xv[4];
            #pragma unroll
            for (int i = 0; i < 4; ++i)
                xv[i] = *(const float4*)(X + (size_t)(row0 + i) * F + k);
            #pragma unroll
            for (int kk = 0; kk < 4; ++kk) {
                float wv[4];
                #pragma unroll
                for (int j = 0; j < 4; ++j) wv[j] = Ws[(k + kk) * F + lane + 32 * j];
                #pragma unroll
                for (int i = 0; i < 4; ++i) {
                    float xs = ((const float*)&xv[i])[kk];
                    #pragma unroll
                    for (int j = 0; j < 4; ++j) acc[i][j] = fmaf(xs, wv[j], acc[i][j]);
                }
            }
        }
        #pragma unroll
        for (int i = 0; i < 4; ++i)
            #pragma unroll
            for (int j = 0; j < 4; ++j)
                Y[(size_t)(row0 + i) * F + lane + 32 * j] = acc[i][j] + bias[lane + 32 * j];
    } else if (row0 < N) {
        for (int r = row0; r < N; ++r) {
            float a[4] = {0.f, 0.f, 0.f, 0.f};
            for (int k = 0; k < F; ++k) {
                float xs = X[(size_t)r * F + k];
                for (int j = 0; j < 4; ++j) a[j] = fmaf(xs, Ws[k * F + lane + 32 * j], a[j]);
            }
            for (int j = 0; j < 4; ++j)
                Y[(size_t)r * F + lane + 32 * j] = a[j] + bias[lane + 32 * j];
        }
    }
}

// ---------------- fused edge phase: logits + segment softmax + aggregate ----------------
// 128 threads per node (thread t = channel h*32+c), 2 nodes per 256-thr block.
// Online softmax per (node, head): each xl[src] row gathered exactly once.

__global__ __launch_bounds__(256) void gat_edge_kernel(
    const float* __restrict__ xl, const float* __restrict__ xr,
    const int* __restrict__ srcs, const int* __restrict__ row_ptr,
    const float* __restrict__ att, const float* __restrict__ bias,
    float* __restrict__ out, int N, int do_relu)
{
    int node = blockIdx.x * 2 + threadIdx.y;
    int t = threadIdx.x;                       // 0..127
    if (node >= N) return;
    float xr_t  = xr[(size_t)node * F + t];
    float att_t = att[t];
    int beg = row_ptr[node], end = row_ptr[node + 1];
    float m = -FLT_MAX, s = 0.f, o = 0.f;
    #pragma unroll 4
    for (int i = beg; i < end; ++i) {
        int sn = srcs[i];                      // broadcast load (same addr across lanes)
        float v = xl[(size_t)sn * F + t];      // 512B coalesced gather
        float e = v + xr_t;
        e = e >= 0.f ? e : 0.2f * e;           // leaky_relu slope 0.2
        float p = e * att_t;
        // reduce over 32 channels within the head group (wave64: masks<32 stay in-group)
        p += __shfl_xor(p, 16);
        p += __shfl_xor(p, 8);
        p += __shfl_xor(p, 4);
        p += __shfl_xor(p, 2);
        p += __shfl_xor(p, 1);
        // online softmax update
        float mn    = fmaxf(m, p);
        float scale = __expf(m - mn);
        float w     = __expf(p - mn);
        s = s * scale + w;
        o = o * scale + w * v;
        m = mn;
    }
    float res = o / (s + 1e-16f) + bias[t];
    if (do_relu) res = fmaxf(res, 0.f);
    out[(size_t)node * F + t] = res;
}

// ---------------- launch ----------------

extern "C" void kernel_launch(void* const* d_in, const int* in_sizes, int n_in,
                              void* d_out, int out_size, void* d_ws, size_t ws_size,
                              hipStream_t stream)
{
    // setup_inputs() dict order
    const float* x    = (const float*)d_in[0];
    const int*   ei   = (const int*)d_in[1];
    const float* Wl1  = (const float*)d_in[2];
    const float* Wr1  = (const float*)d_in[3];
    const float* Wl2  = (const float*)d_in[4];
    const float* Wr2  = (const float*)d_in[5];
    const float* bl1  = (const float*)d_in[6];
    const float* br1  = (const float*)d_in[7];
    const float* bl2  = (const float*)d_in[8];
    const float* br2  = (const float*)d_in[9];
    const float* att1 = (const float*)d_in[10];
    const float* att2 = (const float*)d_in[11];
    const float* b1   = (const float*)d_in[12];
    const float* b2   = (const float*)d_in[13];

    const int N = in_sizes[0] / F;
    const int E = in_sizes[1] / 2;
    const int* src = ei;
    const int* dst = ei + E;

    // workspace carve-out (~81 MB)
    char* ws = (char*)d_ws;
    size_t off = 0;
    auto alloc = [&](size_t bytes) -> void* {
        void* p = ws + off;
        off = (off + bytes + 255) & ~(size_t)255;
        return p;
    };
    float* xl      = (float*)alloc((size_t)N * F * sizeof(float));
    float* xr      = (float*)alloc((size_t)N * F * sizeof(float));
    float* h       = (float*)alloc((size_t)N * F * sizeof(float));
    int*   row_ptr = (int*)alloc((size_t)(N + 1) * sizeof(int));
    int*   deg     = (int*)alloc((size_t)N * sizeof(int));
    int*   cursor  = (int*)alloc((size_t)N * sizeof(int));
    int*   srcs    = (int*)alloc((size_t)E * sizeof(int));

    // CSR build (edge structure shared by both layers)
    hipMemsetAsync(deg, 0, (size_t)N * sizeof(int), stream);
    hipMemsetAsync(cursor, 0, (size_t)N * sizeof(int), stream);
    count_deg_kernel<<<(E + 255) / 256, 256, 0, stream>>>(dst, deg, E);
    exscan_kernel<<<1, 1024, 0, stream>>>(deg, row_ptr, N);
    scatter_kernel<<<(E + 255) / 256, 256, 0, stream>>>(src, dst, row_ptr, cursor, srcs, E);

    const int gemm_blocks = (N + 31) / 32;
    dim3 eb(128, 2);
    const int edge_blocks = (N + 1) / 2;

    // layer 1
    gemm128_kernel<<<gemm_blocks, 256, 0, stream>>>(x, Wl1, bl1, xl, N);
    gemm128_kernel<<<gemm_blocks, 256, 0, stream>>>(x, Wr1, br1, xr, N);
    gat_edge_kernel<<<edge_blocks, eb, 0, stream>>>(xl, xr, srcs, row_ptr, att1, b1, h, N, 1);

    // layer 2 (reuse xl/xr)
    gemm128_kernel<<<gemm_blocks, 256, 0, stream>>>(h, Wl2, bl2, xl, N);
    gemm128_kernel<<<gemm_blocks, 256, 0, stream>>>(h, Wr2, br2, xr, N);
    gat_edge_kernel<<<edge_blocks, eb, 0, stream>>>(xl, xr, srcs, row_ptr, att2, b2, (float*)d_out, N, 0);
}

// Round 2
// 379.974 us; speedup vs baseline: 1.8465x; 1.8465x over previous
//
#include <hip/hip_runtime.h>
#include <hip/hip_bf16.h>
#include <float.h>

#define F 128          // hidden = H*C
#define HEADS 4
#define CPH 32

// ---------------- CSR build ----------------

__global__ void count_deg_kernel(const int* __restrict__ dst, int* __restrict__ deg, int E) {
    int i = blockIdx.x * blockDim.x + threadIdx.x;
    if (i < E) atomicAdd(&deg[dst[i]], 1);
}

// hierarchical scan: per-chunk exclusive scan + chunk sums
__global__ __launch_bounds__(1024) void scan1_kernel(const int* __restrict__ deg,
                                                     int* __restrict__ excl,
                                                     int* __restrict__ bsums, int n) {
    __shared__ int tmp[1024];
    int i = blockIdx.x * 1024 + threadIdx.x;
    int v = (i < n) ? deg[i] : 0;
    tmp[threadIdx.x] = v;
    __syncthreads();
    for (int o = 1; o < 1024; o <<= 1) {
        int a = (threadIdx.x >= o) ? tmp[threadIdx.x - o] : 0;
        __syncthreads();
        tmp[threadIdx.x] += a;
        __syncthreads();
    }
    if (i < n) excl[i] = tmp[threadIdx.x] - v;
    if (threadIdx.x == 1023) bsums[blockIdx.x] = tmp[1023];
}

__global__ __launch_bounds__(1024) void scan2_kernel(int* __restrict__ bsums, int nb) {
    __shared__ int tmp[1024];
    int v = (threadIdx.x < nb) ? bsums[threadIdx.x] : 0;
    tmp[threadIdx.x] = v;
    __syncthreads();
    for (int o = 1; o < 1024; o <<= 1) {
        int a = (threadIdx.x >= o) ? tmp[threadIdx.x - o] : 0;
        __syncthreads();
        tmp[threadIdx.x] += a;
        __syncthreads();
    }
    if (threadIdx.x < nb) bsums[threadIdx.x] = tmp[threadIdx.x] - v;  // exclusive
}

__global__ void scan3_kernel(const int* __restrict__ excl, const int* __restrict__ bsums,
                             int* __restrict__ row_ptr, int n, int E) {
    int i = blockIdx.x * 256 + threadIdx.x;
    if (i < n) row_ptr[i] = excl[i] + bsums[i >> 10];
    if (i == n) row_ptr[n] = E;
}

__global__ void scatter_kernel(const int* __restrict__ src, const int* __restrict__ dst,
                               const int* __restrict__ row_ptr, int* __restrict__ cursor,
                               int* __restrict__ srcs, int E) {
    int i = blockIdx.x * blockDim.x + threadIdx.x;
    if (i < E) {
        int d = dst[i];
        int pos = atomicAdd(&cursor[d], 1);
        srcs[row_ptr[d] + pos] = src[i];
    }
}

// ---------------- fp32 GEMM: Y[N,128] = X[N,128] @ W[128,128] + b ----------------
// W staged in LDS (64KB). 256 thr/block, 64 rows/block, 8x4 register tile per thread.

__global__ __launch_bounds__(256) void gemm128_kernel(
    const float* __restrict__ X, const float* __restrict__ W,
    const float* __restrict__ bias, float* __restrict__ Y, int N)
{
    __shared__ float Ws[F * F];
    for (int i = threadIdx.x; i < F * F; i += 256) Ws[i] = W[i];
    __syncthreads();
    int lane = threadIdx.x & 31;   // output cols: lane + 32*j (conflict-free LDS)
    int grp  = threadIdx.x >> 5;   // row group 0..7, 8 rows each
    int row0 = blockIdx.x * 64 + grp * 8;
    if (row0 + 8 <= N) {
        float acc[8][4] = {};
        for (int k = 0; k < F; k += 4) {
            float4 xv[8];
            #pragma unroll
            for (int i = 0; i < 8; ++i)
                xv[i] = *(const float4*)(X + (size_t)(row0 + i) * F + k);
            #pragma unroll
            for (int kk = 0; kk < 4; ++kk) {
                float wv[4];
                #pragma unroll
                for (int j = 0; j < 4; ++j) wv[j] = Ws[(k + kk) * F + lane + 32 * j];
                #pragma unroll
                for (int i = 0; i < 8; ++i) {
                    float xs = ((const float*)&xv[i])[kk];
                    #pragma unroll
                    for (int j = 0; j < 4; ++j) acc[i][j] = fmaf(xs, wv[j], acc[i][j]);
                }
            }
        }
        #pragma unroll
        for (int i = 0; i < 8; ++i)
            #pragma unroll
            for (int j = 0; j < 4; ++j)
                Y[(size_t)(row0 + i) * F + lane + 32 * j] = acc[i][j] + bias[lane + 32 * j];
    } else if (row0 < N) {
        for (int r = row0; r < N; ++r) {
            float a[4] = {0.f, 0.f, 0.f, 0.f};
            for (int k = 0; k < F; ++k) {
                float xs = X[(size_t)r * F + k];
                for (int j = 0; j < 4; ++j) a[j] = fmaf(xs, Ws[k * F + lane + 32 * j], a[j]);
            }
            for (int j = 0; j < 4; ++j)
                Y[(size_t)r * F + lane + 32 * j] = a[j] + bias[lane + 32 * j];
        }
    }
}

// ---------------- fused edge phase ----------------
// 1 wave per node; thread t owns channels (2t, 2t+1); head = t/16.
// Plain exp (no max subtraction — logits are O(5), exp-safe in fp32, math-identical).
// Unroll-4: 4 independent gather->dot->shfl chains in flight.

__device__ __forceinline__ float edge_logit(float2 v, float2 xr_t, float2 a_t) {
    float e0 = v.x + xr_t.x; e0 = e0 >= 0.f ? e0 : 0.2f * e0;
    float e1 = v.y + xr_t.y; e1 = e1 >= 0.f ? e1 : 0.2f * e1;
    float p = e0 * a_t.x + e1 * a_t.y;
    p += __shfl_xor(p, 8);   // reduce over 16-lane head group
    p += __shfl_xor(p, 4);
    p += __shfl_xor(p, 2);
    p += __shfl_xor(p, 1);
    return p;
}

__global__ __launch_bounds__(256) void gat_edge_kernel(
    const float2* __restrict__ xl2, const float2* __restrict__ xr2,
    const int* __restrict__ srcs, const int* __restrict__ row_ptr,
    const float2* __restrict__ att2, const float2* __restrict__ bias2,
    float2* __restrict__ out2, int N, int do_relu)
{
    int node = blockIdx.x * 4 + threadIdx.y;
    int t = threadIdx.x;                       // 0..63
    if (node >= N) return;
    float2 xr_t = xr2[(size_t)node * 64 + t];
    float2 a_t  = att2[t];
    int beg = row_ptr[node], end = row_ptr[node + 1];
    float s = 0.f;
    float ox = 0.f, oy = 0.f;
    int i = beg;
    for (; i + 4 <= end; i += 4) {
        int sn0 = srcs[i], sn1 = srcs[i + 1], sn2 = srcs[i + 2], sn3 = srcs[i + 3];
        float2 v0 = xl2[(size_t)sn0 * 64 + t];
        float2 v1 = xl2[(size_t)sn1 * 64 + t];
        float2 v2 = xl2[(size_t)sn2 * 64 + t];
        float2 v3 = xl2[(size_t)sn3 * 64 + t];
        float p0 = edge_logit(v0, xr_t, a_t);
        float p1 = edge_logit(v1, xr_t, a_t);
        float p2 = edge_logit(v2, xr_t, a_t);
        float p3 = edge_logit(v3, xr_t, a_t);
        float w0 = __expf(p0), w1 = __expf(p1), w2 = __expf(p2), w3 = __expf(p3);
        s += (w0 + w1) + (w2 + w3);
        ox = fmaf(w0, v0.x, ox); oy = fmaf(w0, v0.y, oy);
        ox = fmaf(w1, v1.x, ox); oy = fmaf(w1, v1.y, oy);
        ox = fmaf(w2, v2.x, ox); oy = fmaf(w2, v2.y, oy);
        ox = fmaf(w3, v3.x, ox); oy = fmaf(w3, v3.y, oy);
    }
    for (; i < end; ++i) {
        int sn = srcs[i];
        float2 v = xl2[(size_t)sn * 64 + t];
        float p = edge_logit(v, xr_t, a_t);
        float w = __expf(p);
        s += w;
        ox = fmaf(w, v.x, ox); oy = fmaf(w, v.y, oy);
    }
    float inv = 1.f / (s + 1e-16f);
    float2 bi = bias2[t];
    float rx = ox * inv + bi.x;
    float ry = oy * inv + bi.y;
    if (do_relu) { rx = fmaxf(rx, 0.f); ry = fmaxf(ry, 0.f); }
    float2 r; r.x = rx; r.y = ry;
    out2[(size_t)node * 64 + t] = r;
}

// ---------------- launch ----------------

extern "C" void kernel_launch(void* const* d_in, const int* in_sizes, int n_in,
                              void* d_out, int out_size, void* d_ws, size_t ws_size,
                              hipStream_t stream)
{
    const float* x    = (const float*)d_in[0];
    const int*   ei   = (const int*)d_in[1];
    const float* Wl1  = (const float*)d_in[2];
    const float* Wr1  = (const float*)d_in[3];
    const float* Wl2  = (const float*)d_in[4];
    const float* Wr2  = (const float*)d_in[5];
    const float* bl1  = (const float*)d_in[6];
    const float* br1  = (const float*)d_in[7];
    const float* bl2  = (const float*)d_in[8];
    const float* br2  = (const float*)d_in[9];
    const float* att1 = (const float*)d_in[10];
    const float* att2 = (const float*)d_in[11];
    const float* b1   = (const float*)d_in[12];
    const float* b2   = (const float*)d_in[13];

    const int N = in_sizes[0] / F;
    const int E = in_sizes[1] / 2;
    const int* src = ei;
    const int* dst = ei + E;

    char* ws = (char*)d_ws;
    size_t off = 0;
    auto alloc = [&](size_t bytes) -> void* {
        void* p = ws + off;
        off = (off + bytes + 255) & ~(size_t)255;
        return p;
    };
    float* xl      = (float*)alloc((size_t)N * F * sizeof(float));
    float* xr      = (float*)alloc((size_t)N * F * sizeof(float));
    float* h       = (float*)alloc((size_t)N * F * sizeof(float));
    int*   row_ptr = (int*)alloc((size_t)(N + 1) * sizeof(int));
    int*   deg     = (int*)alloc((size_t)N * sizeof(int));
    int*   excl    = (int*)alloc((size_t)N * sizeof(int));
    int*   bsums   = (int*)alloc((size_t)1024 * sizeof(int));
    int*   cursor  = (int*)alloc((size_t)N * sizeof(int));
    int*   srcs    = (int*)alloc((size_t)E * sizeof(int));

    // CSR build (edge structure shared by both layers)
    hipMemsetAsync(deg, 0, (size_t)N * sizeof(int), stream);
    hipMemsetAsync(cursor, 0, (size_t)N * sizeof(int), stream);
    count_deg_kernel<<<(E + 255) / 256, 256, 0, stream>>>(dst, deg, E);
    const int nchunks = (N + 1023) / 1024;
    scan1_kernel<<<nchunks, 1024, 0, stream>>>(deg, excl, bsums, N);
    scan2_kernel<<<1, 1024, 0, stream>>>(bsums, nchunks);
    scan3_kernel<<<(N + 256) / 256, 256, 0, stream>>>(excl, bsums, row_ptr, N, E);
    scatter_kernel<<<(E + 255) / 256, 256, 0, stream>>>(src, dst, row_ptr, cursor, srcs, E);

    const int gemm_blocks = (N + 63) / 64;
    dim3 eb(64, 4);
    const int edge_blocks = (N + 3) / 4;

    // layer 1
    gemm128_kernel<<<gemm_blocks, 256, 0, stream>>>(x, Wl1, bl1, xl, N);
    gemm128_kernel<<<gemm_blocks, 256, 0, stream>>>(x, Wr1, br1, xr, N);
    gat_edge_kernel<<<edge_blocks, eb, 0, stream>>>((const float2*)xl, (const float2*)xr,
                                                    srcs, row_ptr, (const float2*)att1,
                                                    (const float2*)b1, (float2*)h, N, 1);

    // layer 2 (reuse xl/xr)
    gemm128_kernel<<<gemm_blocks, 256, 0, stream>>>(h, Wl2, bl2, xl, N);
    gemm128_kernel<<<gemm_blocks, 256, 0, stream>>>(h, Wr2, br2, xr, N);
    gat_edge_kernel<<<edge_blocks, eb, 0, stream>>>((const float2*)xl, (const float2*)xr,
                                                    srcs, row_ptr, (const float2*)att2,
                                                    (const float2*)b2, (float2*)d_out, N, 0);
}

// Round 3
// 345.672 us; speedup vs baseline: 2.0298x; 1.0992x over previous
//
#include <hip/hip_runtime.h>
#include <hip/hip_bf16.h>
#include <float.h>

#define F 128          // hidden = H*C
#define HEADS 4
#define CPH 32

// ---------------- CSR build ----------------

__global__ void count_deg_kernel(const int* __restrict__ dst, int* __restrict__ deg, int E) {
    int i = blockIdx.x * blockDim.x + threadIdx.x;
    if (i < E) atomicAdd(&deg[dst[i]], 1);
}

__global__ __launch_bounds__(1024) void scan1_kernel(const int* __restrict__ deg,
                                                     int* __restrict__ excl,
                                                     int* __restrict__ bsums, int n) {
    __shared__ int tmp[1024];
    int i = blockIdx.x * 1024 + threadIdx.x;
    int v = (i < n) ? deg[i] : 0;
    tmp[threadIdx.x] = v;
    __syncthreads();
    for (int o = 1; o < 1024; o <<= 1) {
        int a = (threadIdx.x >= o) ? tmp[threadIdx.x - o] : 0;
        __syncthreads();
        tmp[threadIdx.x] += a;
        __syncthreads();
    }
    if (i < n) excl[i] = tmp[threadIdx.x] - v;
    if (threadIdx.x == 1023) bsums[blockIdx.x] = tmp[1023];
}

__global__ __launch_bounds__(1024) void scan2_kernel(int* __restrict__ bsums, int nb) {
    __shared__ int tmp[1024];
    int v = (threadIdx.x < nb) ? bsums[threadIdx.x] : 0;
    tmp[threadIdx.x] = v;
    __syncthreads();
    for (int o = 1; o < 1024; o <<= 1) {
        int a = (threadIdx.x >= o) ? tmp[threadIdx.x - o] : 0;
        __syncthreads();
        tmp[threadIdx.x] += a;
        __syncthreads();
    }
    if (threadIdx.x < nb) bsums[threadIdx.x] = tmp[threadIdx.x] - v;  // exclusive
}

__global__ void scan3_kernel(const int* __restrict__ excl, const int* __restrict__ bsums,
                             int* __restrict__ row_ptr, int n, int E) {
    int i = blockIdx.x * 256 + threadIdx.x;
    if (i < n) row_ptr[i] = excl[i] + bsums[i >> 10];
    if (i == n) row_ptr[n] = E;
}

__global__ void scatter_kernel(const int* __restrict__ src, const int* __restrict__ dst,
                               const int* __restrict__ row_ptr, int* __restrict__ cursor,
                               int* __restrict__ srcs, int E) {
    int i = blockIdx.x * blockDim.x + threadIdx.x;
    if (i < E) {
        int d = dst[i];
        int pos = atomicAdd(&cursor[d], 1);
        srcs[row_ptr[d] + pos] = src[i];
    }
}

// ---------------- fused dual fp32 GEMM: Y1 = X@W1+b1, Y2 = X@W2+b2 ----------------
// Both W staged in LDS (128KB). 512 thr/block, 128 rows/block, 8x4x2 register tile.

__global__ __launch_bounds__(512) void dual_gemm128_kernel(
    const float* __restrict__ X,
    const float* __restrict__ W1, const float* __restrict__ bias1,
    const float* __restrict__ W2, const float* __restrict__ bias2,
    float* __restrict__ Y1, float* __restrict__ Y2, int N)
{
    __shared__ float Ws1[F * F];
    __shared__ float Ws2[F * F];
    for (int i = threadIdx.x; i < F * F / 4; i += 512) {
        ((float4*)Ws1)[i] = ((const float4*)W1)[i];
        ((float4*)Ws2)[i] = ((const float4*)W2)[i];
    }
    __syncthreads();
    int lane = threadIdx.x & 31;   // output cols: lane + 32*j (conflict-free LDS)
    int grp  = threadIdx.x >> 5;   // row group 0..15, 8 rows each
    int row0 = blockIdx.x * 128 + grp * 8;
    if (row0 + 8 <= N) {
        float acc1[8][4] = {};
        float acc2[8][4] = {};
        for (int k = 0; k < F; k += 4) {
            float4 xv[8];
            #pragma unroll
            for (int i = 0; i < 8; ++i)
                xv[i] = *(const float4*)(X + (size_t)(row0 + i) * F + k);
            #pragma unroll
            for (int kk = 0; kk < 4; ++kk) {
                float wv1[4], wv2[4];
                #pragma unroll
                for (int j = 0; j < 4; ++j) {
                    wv1[j] = Ws1[(k + kk) * F + lane + 32 * j];
                    wv2[j] = Ws2[(k + kk) * F + lane + 32 * j];
                }
                #pragma unroll
                for (int i = 0; i < 8; ++i) {
                    float xs = ((const float*)&xv[i])[kk];
                    #pragma unroll
                    for (int j = 0; j < 4; ++j) {
                        acc1[i][j] = fmaf(xs, wv1[j], acc1[i][j]);
                        acc2[i][j] = fmaf(xs, wv2[j], acc2[i][j]);
                    }
                }
            }
        }
        #pragma unroll
        for (int i = 0; i < 8; ++i)
            #pragma unroll
            for (int j = 0; j < 4; ++j) {
                Y1[(size_t)(row0 + i) * F + lane + 32 * j] = acc1[i][j] + bias1[lane + 32 * j];
                Y2[(size_t)(row0 + i) * F + lane + 32 * j] = acc2[i][j] + bias2[lane + 32 * j];
            }
    } else if (row0 < N) {
        for (int r = row0; r < N; ++r) {
            float a1[4] = {}, a2[4] = {};
            for (int k = 0; k < F; ++k) {
                float xs = X[(size_t)r * F + k];
                for (int j = 0; j < 4; ++j) {
                    a1[j] = fmaf(xs, Ws1[k * F + lane + 32 * j], a1[j]);
                    a2[j] = fmaf(xs, Ws2[k * F + lane + 32 * j], a2[j]);
                }
            }
            for (int j = 0; j < 4; ++j) {
                Y1[(size_t)r * F + lane + 32 * j] = a1[j] + bias1[lane + 32 * j];
                Y2[(size_t)r * F + lane + 32 * j] = a2[j] + bias2[lane + 32 * j];
            }
        }
    }
}

// ---------------- fused edge phase ----------------
// 1 wave per node. Lane l: half = l>>5 (even/odd edge), cl = l&31 owns channels
// 4cl..4cl+3 (float4 gather, 16B/lane). Head group = 8 lanes -> 3-step shfl reduce.
// Two edges per wave-iteration; halves combined once at the end via shfl_xor(32).
// Plain exp (logits O(5), exp-safe in fp32, math-identical to max-subtracted form).

__global__ __launch_bounds__(256) void gat_edge_kernel(
    const float4* __restrict__ xl4, const float4* __restrict__ xr4,
    const int* __restrict__ srcs, const int* __restrict__ row_ptr,
    const float4* __restrict__ att4, const float4* __restrict__ bias4,
    float4* __restrict__ out4, int N, int do_relu)
{
    int node = blockIdx.x * 4 + threadIdx.y;
    if (node >= N) return;
    int lane = threadIdx.x;        // 0..63
    int cl   = lane & 31;          // channel-quad index
    int half = lane >> 5;          // 0: even edges, 1: odd edges
    float4 xr_t = xr4[(size_t)node * 32 + cl];
    float4 a_t  = att4[cl];
    int beg = row_ptr[node], end = row_ptr[node + 1];
    float s = 0.f;
    float o0 = 0.f, o1 = 0.f, o2 = 0.f, o3 = 0.f;
    #pragma unroll 2
    for (int i = beg; i < end; i += 2) {
        int idx = i + half;
        bool valid = idx < end;
        int sn = srcs[valid ? idx : i];
        float4 v = xl4[(size_t)sn * 32 + cl];
        float e0 = v.x + xr_t.x; e0 = e0 >= 0.f ? e0 : 0.2f * e0;
        float e1 = v.y + xr_t.y; e1 = e1 >= 0.f ? e1 : 0.2f * e1;
        float e2 = v.z + xr_t.z; e2 = e2 >= 0.f ? e2 : 0.2f * e2;
        float e3 = v.w + xr_t.w; e3 = e3 >= 0.f ? e3 : 0.2f * e3;
        float p = fmaf(e3, a_t.w, fmaf(e2, a_t.z, fmaf(e1, a_t.y, e0 * a_t.x)));
        p += __shfl_xor(p, 4);     // reduce over 8-lane head group
        p += __shfl_xor(p, 2);
        p += __shfl_xor(p, 1);
        float w = valid ? __expf(p) : 0.f;
        s += w;
        o0 = fmaf(w, v.x, o0);
        o1 = fmaf(w, v.y, o1);
        o2 = fmaf(w, v.z, o2);
        o3 = fmaf(w, v.w, o3);
    }
    // combine even/odd halves
    s  += __shfl_xor(s, 32);
    o0 += __shfl_xor(o0, 32);
    o1 += __shfl_xor(o1, 32);
    o2 += __shfl_xor(o2, 32);
    o3 += __shfl_xor(o3, 32);
    if (half == 0) {
        float inv = 1.f / (s + 1e-16f);
        float4 bi = bias4[cl];
        float4 r;
        r.x = fmaf(o0, inv, bi.x);
        r.y = fmaf(o1, inv, bi.y);
        r.z = fmaf(o2, inv, bi.z);
        r.w = fmaf(o3, inv, bi.w);
        if (do_relu) {
            r.x = fmaxf(r.x, 0.f); r.y = fmaxf(r.y, 0.f);
            r.z = fmaxf(r.z, 0.f); r.w = fmaxf(r.w, 0.f);
        }
        out4[(size_t)node * 32 + cl] = r;
    }
}

// ---------------- launch ----------------

extern "C" void kernel_launch(void* const* d_in, const int* in_sizes, int n_in,
                              void* d_out, int out_size, void* d_ws, size_t ws_size,
                              hipStream_t stream)
{
    const float* x    = (const float*)d_in[0];
    const int*   ei   = (const int*)d_in[1];
    const float* Wl1  = (const float*)d_in[2];
    const float* Wr1  = (const float*)d_in[3];
    const float* Wl2  = (const float*)d_in[4];
    const float* Wr2  = (const float*)d_in[5];
    const float* bl1  = (const float*)d_in[6];
    const float* br1  = (const float*)d_in[7];
    const float* bl2  = (const float*)d_in[8];
    const float* br2  = (const float*)d_in[9];
    const float* att1 = (const float*)d_in[10];
    const float* att2 = (const float*)d_in[11];
    const float* b1   = (const float*)d_in[12];
    const float* b2   = (const float*)d_in[13];

    const int N = in_sizes[0] / F;
    const int E = in_sizes[1] / 2;
    const int* src = ei;
    const int* dst = ei + E;

    char* ws = (char*)d_ws;
    size_t off = 0;
    auto alloc = [&](size_t bytes) -> void* {
        void* p = ws + off;
        off = (off + bytes + 255) & ~(size_t)255;
        return p;
    };
    float* xl      = (float*)alloc((size_t)N * F * sizeof(float));
    float* xr      = (float*)alloc((size_t)N * F * sizeof(float));
    float* h       = (float*)alloc((size_t)N * F * sizeof(float));
    int*   row_ptr = (int*)alloc((size_t)(N + 1) * sizeof(int));
    int*   deg     = (int*)alloc((size_t)N * sizeof(int));
    int*   excl    = (int*)alloc((size_t)N * sizeof(int));
    int*   bsums   = (int*)alloc((size_t)1024 * sizeof(int));
    int*   cursor  = (int*)alloc((size_t)N * sizeof(int));
    int*   srcs    = (int*)alloc((size_t)E * sizeof(int));

    // CSR build (edge structure shared by both layers)
    hipMemsetAsync(deg, 0, (size_t)N * sizeof(int), stream);
    hipMemsetAsync(cursor, 0, (size_t)N * sizeof(int), stream);
    count_deg_kernel<<<(E + 255) / 256, 256, 0, stream>>>(dst, deg, E);
    const int nchunks = (N + 1023) / 1024;
    scan1_kernel<<<nchunks, 1024, 0, stream>>>(deg, excl, bsums, N);
    scan2_kernel<<<1, 1024, 0, stream>>>(bsums, nchunks);
    scan3_kernel<<<(N + 256) / 256, 256, 0, stream>>>(excl, bsums, row_ptr, N, E);
    scatter_kernel<<<(E + 255) / 256, 256, 0, stream>>>(src, dst, row_ptr, cursor, srcs, E);

    const int dual_blocks = (N + 127) / 128;
    dim3 eb(64, 4);
    const int edge_blocks = (N + 3) / 4;

    // layer 1
    dual_gemm128_kernel<<<dual_blocks, 512, 0, stream>>>(x, Wl1, bl1, Wr1, br1, xl, xr, N);
    gat_edge_kernel<<<edge_blocks, eb, 0, stream>>>((const float4*)xl, (const float4*)xr,
                                                    srcs, row_ptr, (const float4*)att1,
                                                    (const float4*)b1, (float4*)h, N, 1);

    // layer 2 (reuse xl/xr)
    dual_gemm128_kernel<<<dual_blocks, 512, 0, stream>>>(h, Wl2, bl2, Wr2, br2, xl, xr, N);
    gat_edge_kernel<<<edge_blocks, eb, 0, stream>>>((const float4*)xl, (const float4*)xr,
                                                    srcs, row_ptr, (const float4*)att2,
                                                    (const float4*)b2, (float4*)d_out, N, 0);
}